// Round 4
// baseline (22846.553 us; speedup 1.0000x reference)
//
#include <hip/hip_runtime.h>
#include <hip/hip_bf16.h>
#include <stdint.h>

// Problem dims
#define Bg 256
#define Tg 64
#define Pg 10

__device__ __forceinline__ uint16_t f2bf(float f) {
    union { float f; uint32_t i; } v; v.f = f;
    uint32_t lsb = (v.i >> 16) & 1u;
    return (uint16_t)((v.i + 0x7FFFu + lsb) >> 16);
}
__device__ __forceinline__ float bf2f(uint16_t u) {
    union { uint32_t i; float f; } v; v.i = ((uint32_t)u) << 16; return v.f;
}
__device__ __forceinline__ float sigmoidf_(float x) {
    return 1.0f / (1.0f + __expf(-x));
}

// ---------------------------------------------------------------------------
// SGCN: one block per (b,t). 128 threads. All intermediates in LDS (fp32).
// Inputs fp32; z written bf16 to workspace (bounded tanh outputs, ~1e-3 err).
// ---------------------------------------------------------------------------
__global__ __launch_bounds__(128) void sgcn_kernel(
    const float* __restrict__ x,
    const float* __restrict__ A_pos,
    const float* __restrict__ A_neg,
    const float* __restrict__ Wpb,
    const float* __restrict__ bpb,
    const float* __restrict__ Wnb,
    const float* __restrict__ bnb,
    const float* __restrict__ Wpd,
    const float* __restrict__ bpd,
    const float* __restrict__ Wnd,
    const float* __restrict__ bnd,
    uint16_t* __restrict__ z)
{
    __shared__ float As[2][10][10];     // normalized adjacencies (pos, neg)
    __shared__ float rs[2][10];
    __shared__ __align__(16) float Xs[10][128];      // x tile
    __shared__ __align__(16) float XA[2][10][128];   // An @ x
    __shared__ float Hh[2][10][32];     // h_pos / h_neg
    __shared__ float G[4][10][32];      // ap_p, ap_n, an_p, an_n
    __shared__ float NH[2][10][32];

    const int tid = threadIdx.x;
    const int bt  = blockIdx.x;        // bt = b*64 + t

    // load x tile (fp32, float4-vectorized: 1280 floats = 320 float4)
    {
        const float4* xb4 = reinterpret_cast<const float4*>(x + (size_t)bt * 1280);
        float4* xs4 = reinterpret_cast<float4*>(&Xs[0][0]);
        for (int e = tid; e < 320; e += 128)
            xs4[e] = xb4[e];
    }
    // load raw adjacencies (200 entries, 128 threads: strided loop)
    for (int e = tid; e < 200; e += 128) {
        int s = e / 100, r = e - s * 100;
        const float* A = s ? A_neg : A_pos;
        As[s][r / 10][r % 10] = A[(size_t)bt * 100 + r];
    }
    __syncthreads();
    if (tid < 20) {
        int s = tid / 10, i = tid - s * 10;
        float sum = 0.f;
        #pragma unroll
        for (int j = 0; j < 10; ++j) sum += As[s][i][j];
        rs[s][i] = 1.0f / (sum + 1e-8f);
    }
    __syncthreads();
    for (int e = tid; e < 200; e += 128) {
        int s = e / 100, r = e - s * 100;
        As[s][r / 10][r % 10] *= rs[s][r / 10];
    }
    __syncthreads();

    // XA[s][i][d] = sum_j An[s][i][j] * Xs[j][d]
    for (int o = tid; o < 2560; o += 128) {
        int s = (o >= 1280);
        int rem = o - s * 1280;
        int i = rem >> 7, d = rem & 127;
        float acc = 0.f;
        #pragma unroll
        for (int j = 0; j < 10; ++j) acc += As[s][i][j] * Xs[j][d];
        XA[s][i][d] = acc;
    }
    __syncthreads();

    // base layer: H[s][i][k] = tanh(cat([XA, X]) @ W_base + b)
    for (int w = tid; w < 160; w += 128) {
        int s = (w >= 80);
        int rem = w - s * 80;
        int i = rem >> 3, k0 = (rem & 7) << 2;
        const float* Wb = s ? Wnb : Wpb;
        const float* bb = s ? bnb : bpb;
        float a0 = 0.f, a1 = 0.f, a2 = 0.f, a3 = 0.f;
        for (int d = 0; d < 128; ++d) {
            float xa = XA[s][i][d];
            float4 wv = *reinterpret_cast<const float4*>(Wb + d * 32 + k0);
            a0 += xa * wv.x; a1 += xa * wv.y;
            a2 += xa * wv.z; a3 += xa * wv.w;
        }
        for (int d = 0; d < 128; ++d) {
            float xv = Xs[i][d];
            float4 wv = *reinterpret_cast<const float4*>(Wb + (128 + d) * 32 + k0);
            a0 += xv * wv.x; a1 += xv * wv.y;
            a2 += xv * wv.z; a3 += xv * wv.w;
        }
        Hh[s][i][k0 + 0] = tanhf(a0 + bb[k0 + 0]);
        Hh[s][i][k0 + 1] = tanhf(a1 + bb[k0 + 1]);
        Hh[s][i][k0 + 2] = tanhf(a2 + bb[k0 + 2]);
        Hh[s][i][k0 + 3] = tanhf(a3 + bb[k0 + 3]);
    }
    __syncthreads();

    // two deep layers
    for (int l = 0; l < 2; ++l) {
        // aggregations: G[0]=Anp@Hp  G[1]=Anp@Hn  G[2]=Ann@Hp  G[3]=Ann@Hn
        for (int o = tid; o < 1280; o += 128) {
            int gi = o / 320;
            int rem = o - gi * 320;
            int i = rem >> 5, k = rem & 31;
            int a = gi >> 1, hsel = gi & 1;
            float acc = 0.f;
            #pragma unroll
            for (int j = 0; j < 10; ++j) acc += As[a][i][j] * Hh[hsel][j][k];
            G[gi][i][k] = acc;
        }
        __syncthreads();
        // new H: concat order [G0,G1,G2,G3,Hp,Hn,Hself] (7 x 32) @ W_deep[l]
        for (int w = tid; w < 160; w += 128) {
            int s = (w >= 80);
            int rem = w - s * 80;
            int i = rem >> 3, k0 = (rem & 7) << 2;
            const float* Wd = (s ? Wnd : Wpd) + l * 7168;
            const float* bd = (s ? bnd : bpd) + l * 32;
            float a0 = 0.f, a1 = 0.f, a2 = 0.f, a3 = 0.f;
            #pragma unroll
            for (int b7 = 0; b7 < 7; ++b7) {
                const float* u = (b7 < 4) ? &G[b7][i][0]
                               : (b7 < 6) ? &Hh[b7 - 4][i][0]
                                          : &Hh[s][i][0];
                for (int rk = 0; rk < 32; ++rk) {
                    float uv = u[rk];
                    float4 wv = *reinterpret_cast<const float4*>(
                        Wd + (b7 * 32 + rk) * 32 + k0);
                    a0 += uv * wv.x; a1 += uv * wv.y;
                    a2 += uv * wv.z; a3 += uv * wv.w;
                }
            }
            NH[s][i][k0 + 0] = tanhf(a0 + bd[k0 + 0]);
            NH[s][i][k0 + 1] = tanhf(a1 + bd[k0 + 1]);
            NH[s][i][k0 + 2] = tanhf(a2 + bd[k0 + 2]);
            NH[s][i][k0 + 3] = tanhf(a3 + bd[k0 + 3]);
        }
        __syncthreads();
        for (int o = tid; o < 640; o += 128)
            (&Hh[0][0][0])[o] = (&NH[0][0][0])[o];
        __syncthreads();
    }

    // z = cat([h_pos, h_neg], -1), stored bf16 in workspace
    {
        uint16_t* zb = z + (size_t)bt * 640;
        for (int o = tid; o < 640; o += 128) {
            int i = o >> 6, cc = o & 63;
            int s = cc >> 5, k = cc & 31;
            zb[o] = f2bf(Hh[s][i][k]);
        }
    }
}

// ---------------------------------------------------------------------------
// LSTM: one block per (player, 4-game chunk). 256 threads; thread g owns gate
// row g. fp32 global weights are round-packed to bf16 register pairs (64
// VGPRs). Output written as FP32 (reference output dtype is float32).
// ---------------------------------------------------------------------------
__global__ __launch_bounds__(256) void lstm_kernel(
    const uint16_t* __restrict__ zin,
    const float* __restrict__ W_ih,
    const float* __restrict__ W_hh,
    const float* __restrict__ b_ih,
    const float* __restrict__ b_hh,
    float* __restrict__ out)
{
    __shared__ __align__(16) float zh[4][128];   // per game: [z(64) | h(64)]
    __shared__ float gbuf[4][256];               // gate pre-activations

    const int tid = threadIdx.x;
    const int p   = blockIdx.x % 10;
    const int b0  = (blockIdx.x / 10) * 4;

    // stage this gate-row's weights: fp32 -> bf16 pairs in u32
    uint32_t wreg[64];
    {
        const float4* wi4 = reinterpret_cast<const float4*>(
            W_ih + ((size_t)p * 256 + tid) * 64);
        const float4* wh4 = reinterpret_cast<const float4*>(
            W_hh + ((size_t)p * 256 + tid) * 64);
        #pragma unroll
        for (int m = 0; m < 16; ++m) {
            float4 v = wi4[m];
            wreg[m * 2 + 0] = ((uint32_t)f2bf(v.y) << 16) | f2bf(v.x);
            wreg[m * 2 + 1] = ((uint32_t)f2bf(v.w) << 16) | f2bf(v.z);
        }
        #pragma unroll
        for (int m = 0; m < 16; ++m) {
            float4 v = wh4[m];
            wreg[32 + m * 2 + 0] = ((uint32_t)f2bf(v.y) << 16) | f2bf(v.x);
            wreg[32 + m * 2 + 1] = ((uint32_t)f2bf(v.w) << 16) | f2bf(v.z);
        }
    }
    const float bias = b_ih[p * 256 + tid] + b_hh[p * 256 + tid];
    const int n = tid >> 6, kk = tid & 63;
    float creg = 0.f;
    zh[n][64 + kk] = 0.f;
    __syncthreads();

    for (int t = 0; t < 64; ++t) {
        // load z_t for the 4 games (bf16 from workspace)
        zh[n][kk] = bf2f(zin[((size_t)(b0 + n) * 64 + t) * 640 + p * 64 + kk]);
        __syncthreads();

        // gates: thread g computes gate g for all 4 games
        float a0 = bias, a1 = bias, a2 = bias, a3 = bias;
        #pragma unroll
        for (int jg = 0; jg < 32; ++jg) {
            uint32_t wlo = wreg[jg * 2], whi = wreg[jg * 2 + 1];
            float w0 = __uint_as_float(wlo << 16);
            float w1 = __uint_as_float(wlo & 0xFFFF0000u);
            float w2 = __uint_as_float(whi << 16);
            float w3 = __uint_as_float(whi & 0xFFFF0000u);
            float4 z0 = *reinterpret_cast<const float4*>(&zh[0][jg * 4]);
            float4 z1 = *reinterpret_cast<const float4*>(&zh[1][jg * 4]);
            float4 z2 = *reinterpret_cast<const float4*>(&zh[2][jg * 4]);
            float4 z3 = *reinterpret_cast<const float4*>(&zh[3][jg * 4]);
            a0 += w0 * z0.x + w1 * z0.y + w2 * z0.z + w3 * z0.w;
            a1 += w0 * z1.x + w1 * z1.y + w2 * z1.z + w3 * z1.w;
            a2 += w0 * z2.x + w1 * z2.y + w2 * z2.z + w3 * z2.w;
            a3 += w0 * z3.x + w1 * z3.y + w2 * z3.z + w3 * z3.w;
        }
        gbuf[0][tid] = a0; gbuf[1][tid] = a1;
        gbuf[2][tid] = a2; gbuf[3][tid] = a3;
        __syncthreads();

        // cell update: thread (n,kk) owns hidden unit kk of game n
        {
            float gi = gbuf[n][kk];
            float gf = gbuf[n][64 + kk];
            float gg = gbuf[n][128 + kk];
            float go = gbuf[n][192 + kk];
            float cn = sigmoidf_(gf) * creg + sigmoidf_(gi) * tanhf(gg);
            float hn = sigmoidf_(go) * tanhf(cn);
            creg = cn;
            zh[n][64 + kk] = hn;
            out[((size_t)(b0 + n) * 64 + t) * 640 + p * 64 + kk] = hn;  // fp32!
        }
        __syncthreads();
    }
}

extern "C" void kernel_launch(void* const* d_in, const int* in_sizes, int n_in,
                              void* d_out, int out_size, void* d_ws, size_t ws_size,
                              hipStream_t stream) {
    const float* x     = (const float*)d_in[0];
    const float* A_pos = (const float*)d_in[1];
    const float* A_neg = (const float*)d_in[2];
    const float* Wpb   = (const float*)d_in[3];
    const float* bpb   = (const float*)d_in[4];
    const float* Wnb   = (const float*)d_in[5];
    const float* bnb   = (const float*)d_in[6];
    const float* Wpd   = (const float*)d_in[7];
    const float* bpd   = (const float*)d_in[8];
    const float* Wnd   = (const float*)d_in[9];
    const float* bnd   = (const float*)d_in[10];
    const float* Wih   = (const float*)d_in[11];
    const float* Whh   = (const float*)d_in[12];
    const float* bih   = (const float*)d_in[13];
    const float* bhh   = (const float*)d_in[14];

    uint16_t* z = (uint16_t*)d_ws;     // [B,T,P,64] bf16 = 20 MB
    float* out  = (float*)d_out;       // [B,T,P,64] fp32 = 40 MB

    sgcn_kernel<<<Bg * Tg, 128, 0, stream>>>(
        x, A_pos, A_neg, Wpb, bpb, Wnb, bnb, Wpd, bpd, Wnd, bnd, z);
    lstm_kernel<<<(Bg / 4) * Pg, 256, 0, stream>>>(
        z, Wih, Whh, bih, bhh, out);
}

// Round 5
// 1342.962 us; speedup vs baseline: 17.0121x; 17.0121x over previous
//
#include <hip/hip_runtime.h>
#include <hip/hip_bf16.h>
#include <stdint.h>

// Problem dims
#define Bg 256
#define Tg 64
#define Pg 10
#define NG 4   // graphs per sgcn block

__device__ __forceinline__ uint16_t f2bf(float f) {
    union { float f; uint32_t i; } v; v.f = f;
    uint32_t lsb = (v.i >> 16) & 1u;
    return (uint16_t)((v.i + 0x7FFFu + lsb) >> 16);
}
__device__ __forceinline__ float bf2f(uint16_t u) {
    union { uint32_t i; float f; } v; v.i = ((uint32_t)u) << 16; return v.f;
}
__device__ __forceinline__ float sigmoidf_(float x) {
    return 1.0f / (1.0f + __expf(-x));
}

// ---------------------------------------------------------------------------
// SGCN v2: 4 graphs per block, 256 threads. Weights staged in LDS (fp32,
// coalesced float4, one reusable 64KB buffer). Thread = (graph g, sign s,
// col k): owns 10-node accumulators in registers; activation reads are LDS
// broadcasts; weight reads are stride-1 conflict-free. Base layer uses
// (An@X)@Wtop == An@(X@Wtop) so no [10][128] aggregate is materialized.
// ---------------------------------------------------------------------------
__global__ __launch_bounds__(256) void sgcn_kernel(
    const float* __restrict__ x,
    const float* __restrict__ A_pos,
    const float* __restrict__ A_neg,
    const float* __restrict__ Wpb,
    const float* __restrict__ bpb,
    const float* __restrict__ Wnb,
    const float* __restrict__ bnb,
    const float* __restrict__ Wpd,
    const float* __restrict__ bpd,
    const float* __restrict__ Wnd,
    const float* __restrict__ bnd,
    uint16_t* __restrict__ z)
{
    __shared__ __align__(16) float WL[16384];            // 64 KB weight stage
    __shared__ float As[NG][2][10][10];                  // normalized adj
    __shared__ float rsv[NG][2][10];
    __shared__ __align__(16) float Xs[NG][10][128];      // 20 KB
    __shared__ __align__(16) float Hh[NG][2][10][32];    // 10 KB
    __shared__ __align__(16) float Gc[NG][4][10][32];    // 20 KB aggregates
    __shared__ __align__(16) float NH[NG][2][10][32];    // 10 KB

    const int tid = threadIdx.x;
    const int bt0 = blockIdx.x * NG;
    const int g = tid >> 6;          // wave-uniform graph
    const int s = (tid >> 5) & 1;    // sign
    const int k = tid & 31;          // output column

    // ---- stage base weights: [s][d][k] flat copy, fully coalesced ----
    {
        const float4* wp = reinterpret_cast<const float4*>(Wpb);
        const float4* wn = reinterpret_cast<const float4*>(Wnb);
        float4* wl = reinterpret_cast<float4*>(WL);
        for (int e = tid; e < 4096; e += 256)
            wl[e] = (e < 2048) ? wp[e] : wn[e - 2048];
    }
    // ---- load X (fp32, float4) ----
    {
        float4* xs = reinterpret_cast<float4*>(&Xs[0][0][0]);
        for (int e = tid; e < NG * 320; e += 256) {
            int gg = e / 320, r = e - gg * 320;
            xs[e] = reinterpret_cast<const float4*>(
                x + (size_t)(bt0 + gg) * 1280)[r];
        }
    }
    // ---- load raw adjacencies ----
    for (int e = tid; e < NG * 200; e += 256) {
        int gg = e / 200, r = e - gg * 200;
        int sg = r / 100, rr = r - sg * 100;
        (&As[gg][sg][0][0])[rr] =
            (sg ? A_neg : A_pos)[(size_t)(bt0 + gg) * 100 + rr];
    }
    __syncthreads();
    if (tid < NG * 20) {
        int gg = tid / 20, r = tid % 20, sg = r / 10, i = r % 10;
        float sum = 0.f;
        #pragma unroll
        for (int j = 0; j < 10; ++j) sum += As[gg][sg][i][j];
        rsv[gg][sg][i] = 1.0f / (sum + 1e-8f);
    }
    __syncthreads();
    for (int e = tid; e < NG * 200; e += 256) {
        int gg = e / 200, r = e - gg * 200;
        int sg = r / 100, rr = r - sg * 100;
        As[gg][sg][rr / 10][rr % 10] *= rsv[gg][sg][rr / 10];
    }
    __syncthreads();

    // ---- base layer: Y = X@Wtop, Z = X@Wbot (registers), then ----
    // ---- H[i] = tanh(sum_j An[i][j]*Y[j] + Z[i] + b)            ----
    {
        float accY[10], accZ[10];
        #pragma unroll
        for (int i = 0; i < 10; ++i) { accY[i] = 0.f; accZ[i] = 0.f; }
        const float* Wt = &WL[s * 8192 + k];
        #pragma unroll 2
        for (int d = 0; d < 128; d += 2) {
            float wt0 = Wt[d * 32],         wt1 = Wt[d * 32 + 32];
            float wb0 = Wt[(d + 128) * 32], wb1 = Wt[(d + 128) * 32 + 32];
            #pragma unroll
            for (int i = 0; i < 10; ++i) {
                float2 xv = *reinterpret_cast<const float2*>(&Xs[g][i][d]);
                accY[i] += xv.x * wt0 + xv.y * wt1;
                accZ[i] += xv.x * wb0 + xv.y * wb1;
            }
        }
        float bb = (s ? bnb : bpb)[k];
        #pragma unroll
        for (int i = 0; i < 10; ++i) {
            float acc = accZ[i] + bb;
            #pragma unroll
            for (int j = 0; j < 10; ++j)
                acc += As[g][s][i][j] * accY[j];
            Hh[g][s][i][k] = tanhf(acc);
        }
    }
    __syncthreads();

    // ---- two deep layers ----
    for (int l = 0; l < 2; ++l) {
        // restage deep weights [s][rk][k]: 14336 floats, coalesced
        {
            const float4* wp = reinterpret_cast<const float4*>(Wpd + l * 7168);
            const float4* wn = reinterpret_cast<const float4*>(Wnd + l * 7168);
            float4* wl = reinterpret_cast<float4*>(WL);
            for (int e = tid; e < 3584; e += 256)
                wl[e] = (e < 1792) ? wp[e] : wn[e - 1792];
        }
        // aggregations: thread s computes gi = 2s (hsel=0) and 2s+1 (hsel=1)
        #pragma unroll
        for (int i = 0; i < 10; ++i) {
            float a[10];
            #pragma unroll
            for (int j = 0; j < 10; ++j) a[j] = As[g][s][i][j];
            float acc0 = 0.f, acc1 = 0.f;
            #pragma unroll
            for (int j = 0; j < 10; ++j) {
                acc0 += a[j] * Hh[g][0][j][k];
                acc1 += a[j] * Hh[g][1][j][k];
            }
            Gc[g][s * 2 + 0][i][k] = acc0;
            Gc[g][s * 2 + 1][i][k] = acc1;
        }
        __syncthreads();   // WL restaged + Gc ready

        // dot: concat blocks [G0,G1,G2,G3,Hp,Hn,Hself(s)] @ Wdeep
        {
            float acc[10];
            float bb = (s ? bnd : bpd)[l * 32 + k];
            #pragma unroll
            for (int i = 0; i < 10; ++i) acc[i] = bb;
            const float* Wd = &WL[s * 7168 + k];
            for (int b7 = 0; b7 < 7; ++b7) {
                const float* u = (b7 < 4) ? &Gc[g][b7][0][0]
                               : (b7 < 6) ? &Hh[g][b7 - 4][0][0]
                                          : &Hh[g][s][0][0];
                const float* w = Wd + b7 * 32 * 32;
                #pragma unroll 2
                for (int c = 0; c < 32; c += 2) {
                    float w0 = w[c * 32], w1 = w[c * 32 + 32];
                    #pragma unroll
                    for (int i = 0; i < 10; ++i) {
                        float2 uv = *reinterpret_cast<const float2*>(
                            u + i * 32 + c);
                        acc[i] += uv.x * w0 + uv.y * w1;
                    }
                }
            }
            #pragma unroll
            for (int i = 0; i < 10; ++i)
                NH[g][s][i][k] = tanhf(acc[i]);
        }
        __syncthreads();
        // commit NH -> Hh (same flat layout)
        for (int e = tid; e < NG * 640; e += 256)
            (&Hh[0][0][0][0])[e] = (&NH[0][0][0][0])[e];
        __syncthreads();
    }

    // ---- z = cat([h_pos, h_neg], -1) as bf16 ----
    {
        uint16_t* zb = z + (size_t)bt0 * 640;
        for (int e = tid; e < NG * 640; e += 256) {
            int gg = e / 640, r = e - gg * 640;
            int i = r >> 6, cc = r & 63, ss = cc >> 5, kk2 = cc & 31;
            zb[e] = f2bf(Hh[gg][ss][i][kk2]);
        }
    }
}

// ---------------------------------------------------------------------------
// LSTM: unchanged from round 4 (passed; ~0.4 ms — next round's target).
// ---------------------------------------------------------------------------
__global__ __launch_bounds__(256) void lstm_kernel(
    const uint16_t* __restrict__ zin,
    const float* __restrict__ W_ih,
    const float* __restrict__ W_hh,
    const float* __restrict__ b_ih,
    const float* __restrict__ b_hh,
    float* __restrict__ out)
{
    __shared__ __align__(16) float zh[4][128];   // per game: [z(64) | h(64)]
    __shared__ float gbuf[4][256];               // gate pre-activations

    const int tid = threadIdx.x;
    const int p   = blockIdx.x % 10;
    const int b0  = (blockIdx.x / 10) * 4;

    uint32_t wreg[64];
    {
        const float4* wi4 = reinterpret_cast<const float4*>(
            W_ih + ((size_t)p * 256 + tid) * 64);
        const float4* wh4 = reinterpret_cast<const float4*>(
            W_hh + ((size_t)p * 256 + tid) * 64);
        #pragma unroll
        for (int m = 0; m < 16; ++m) {
            float4 v = wi4[m];
            wreg[m * 2 + 0] = ((uint32_t)f2bf(v.y) << 16) | f2bf(v.x);
            wreg[m * 2 + 1] = ((uint32_t)f2bf(v.w) << 16) | f2bf(v.z);
        }
        #pragma unroll
        for (int m = 0; m < 16; ++m) {
            float4 v = wh4[m];
            wreg[32 + m * 2 + 0] = ((uint32_t)f2bf(v.y) << 16) | f2bf(v.x);
            wreg[32 + m * 2 + 1] = ((uint32_t)f2bf(v.w) << 16) | f2bf(v.z);
        }
    }
    const float bias = b_ih[p * 256 + tid] + b_hh[p * 256 + tid];
    const int n = tid >> 6, kk = tid & 63;
    float creg = 0.f;
    zh[n][64 + kk] = 0.f;
    __syncthreads();

    for (int t = 0; t < 64; ++t) {
        zh[n][kk] = bf2f(zin[((size_t)(b0 + n) * 64 + t) * 640 + p * 64 + kk]);
        __syncthreads();

        float a0 = bias, a1 = bias, a2 = bias, a3 = bias;
        #pragma unroll
        for (int jg = 0; jg < 32; ++jg) {
            uint32_t wlo = wreg[jg * 2], whi = wreg[jg * 2 + 1];
            float w0 = __uint_as_float(wlo << 16);
            float w1 = __uint_as_float(wlo & 0xFFFF0000u);
            float w2 = __uint_as_float(whi << 16);
            float w3 = __uint_as_float(whi & 0xFFFF0000u);
            float4 z0 = *reinterpret_cast<const float4*>(&zh[0][jg * 4]);
            float4 z1 = *reinterpret_cast<const float4*>(&zh[1][jg * 4]);
            float4 z2 = *reinterpret_cast<const float4*>(&zh[2][jg * 4]);
            float4 z3 = *reinterpret_cast<const float4*>(&zh[3][jg * 4]);
            a0 += w0 * z0.x + w1 * z0.y + w2 * z0.z + w3 * z0.w;
            a1 += w0 * z1.x + w1 * z1.y + w2 * z1.z + w3 * z1.w;
            a2 += w0 * z2.x + w1 * z2.y + w2 * z2.z + w3 * z2.w;
            a3 += w0 * z3.x + w1 * z3.y + w2 * z3.z + w3 * z3.w;
        }
        gbuf[0][tid] = a0; gbuf[1][tid] = a1;
        gbuf[2][tid] = a2; gbuf[3][tid] = a3;
        __syncthreads();

        {
            float gi = gbuf[n][kk];
            float gf = gbuf[n][64 + kk];
            float gg = gbuf[n][128 + kk];
            float go = gbuf[n][192 + kk];
            float cn = sigmoidf_(gf) * creg + sigmoidf_(gi) * tanhf(gg);
            float hn = sigmoidf_(go) * tanhf(cn);
            creg = cn;
            zh[n][64 + kk] = hn;
            out[((size_t)(b0 + n) * 64 + t) * 640 + p * 64 + kk] = hn;
        }
        __syncthreads();
    }
}

extern "C" void kernel_launch(void* const* d_in, const int* in_sizes, int n_in,
                              void* d_out, int out_size, void* d_ws, size_t ws_size,
                              hipStream_t stream) {
    const float* x     = (const float*)d_in[0];
    const float* A_pos = (const float*)d_in[1];
    const float* A_neg = (const float*)d_in[2];
    const float* Wpb   = (const float*)d_in[3];
    const float* bpb   = (const float*)d_in[4];
    const float* Wnb   = (const float*)d_in[5];
    const float* bnb   = (const float*)d_in[6];
    const float* Wpd   = (const float*)d_in[7];
    const float* bpd   = (const float*)d_in[8];
    const float* Wnd   = (const float*)d_in[9];
    const float* bnd   = (const float*)d_in[10];
    const float* Wih   = (const float*)d_in[11];
    const float* Whh   = (const float*)d_in[12];
    const float* bih   = (const float*)d_in[13];
    const float* bhh   = (const float*)d_in[14];

    uint16_t* z = (uint16_t*)d_ws;     // [B,T,P,64] bf16 = 20 MB
    float* out  = (float*)d_out;       // [B,T,P,64] fp32 = 40 MB

    sgcn_kernel<<<(Bg * Tg) / NG, 256, 0, stream>>>(
        x, A_pos, A_neg, Wpb, bpb, Wnb, bnb, Wpd, bpd, Wnd, bnd, z);
    lstm_kernel<<<(Bg / 4) * Pg, 256, 0, stream>>>(
        z, Wih, Whh, bih, bhh, out);
}